// Round 1
// baseline (2904.672 us; speedup 1.0000x reference)
//
#include <hip/hip_runtime.h>
#include <cstdint>
#include <cstddef>

#define BATCH 16
#define CIN   1024
#define CH    512
#define HW    4096

static constexpr float LN_EPS = 1e-5f;

__device__ __forceinline__ float sigmoidf_(float v) { return 1.0f / (1.0f + __expf(-v)); }

// ---------------------------------------------------------------------------
// Fused 1x1-conv GEMM: Y[o,n] = relu(sum_c W[o,c] * x[b,c,n])
// Stacked M = 1537 rows: [0,512)=w_vr -> input_x (d_out region A)
//                        [512,1024)=w_ql -> spatial sums into gmean (atomics)
//                        [1024,1536)=w_vl -> theta_x (d_out region B)
//                        row 1536 = w_qr -> mask_pre (ws)
// Classic 128x128 tile, BK=8, 256 threads, 8x8 micro-tile per thread.
// ---------------------------------------------------------------------------
__global__ __launch_bounds__(256) void gemm_conv(
    const float* __restrict__ x,
    const float* __restrict__ w_qr,
    const float* __restrict__ w_vr,
    const float* __restrict__ w_ql,
    const float* __restrict__ w_vl,
    float* __restrict__ dout,
    float* __restrict__ maskp,
    float* __restrict__ gmean)
{
    const int b  = blockIdx.z;
    const int mt = blockIdx.y;
    const int n0 = blockIdx.x * 128;

    const float* Wsrc; int rows, type, o0;
    if (mt < 4)       { Wsrc = w_vr; rows = 512; type = 0; o0 = mt * 128; }
    else if (mt < 8)  { Wsrc = w_ql; rows = 512; type = 1; o0 = (mt - 4) * 128; }
    else if (mt < 12) { Wsrc = w_vl; rows = 512; type = 2; o0 = (mt - 8) * 128; }
    else              { Wsrc = w_qr; rows = 1;   type = 3; o0 = 0; }

    __shared__ float As[8][128];
    __shared__ float Bs[8][128];
    __shared__ float red[128][17];   // +1 pad: conflict-free column reduce

    const int tid = threadIdx.x;
    const int tx = tid & 15;
    const int ty = tid >> 4;

    float acc[8][8];
#pragma unroll
    for (int i = 0; i < 8; ++i)
#pragma unroll
        for (int j = 0; j < 8; ++j) acc[i][j] = 0.f;

    const int arow = tid >> 1;          // 0..127
    const int ac4  = (tid & 1) << 2;    // 0 or 4
    const int brow = tid >> 5;          // 0..7
    const int bn4  = (tid & 31) << 2;   // 0..124

    const float* xB = x + (size_t)b * CIN * HW + n0;
    const bool a_valid = (o0 + arow) < rows;
    const float* aptr = Wsrc + (size_t)(o0 + arow) * CIN + ac4;

    for (int c0 = 0; c0 < CIN; c0 += 8) {
        float4 av = make_float4(0.f, 0.f, 0.f, 0.f);
        if (a_valid) av = *(const float4*)(aptr + c0);
        float4 bv = *(const float4*)(xB + (size_t)(c0 + brow) * HW + bn4);
        __syncthreads();   // previous iteration's compute done before overwrite
        As[ac4 + 0][arow] = av.x; As[ac4 + 1][arow] = av.y;
        As[ac4 + 2][arow] = av.z; As[ac4 + 3][arow] = av.w;
        *(float4*)&Bs[brow][bn4] = bv;
        __syncthreads();
#pragma unroll
        for (int k = 0; k < 8; ++k) {
            float areg[8], breg[8];
#pragma unroll
            for (int i = 0; i < 8; ++i) areg[i] = As[k][ty * 8 + i];
#pragma unroll
            for (int j = 0; j < 8; ++j) breg[j] = Bs[k][tx * 8 + j];
#pragma unroll
            for (int i = 0; i < 8; ++i)
#pragma unroll
                for (int j = 0; j < 8; ++j)
                    acc[i][j] = fmaf(areg[i], breg[j], acc[i][j]);
        }
    }

    // ReLU (all four conv outputs are relu'd in the reference)
#pragma unroll
    for (int i = 0; i < 8; ++i)
#pragma unroll
        for (int j = 0; j < 8; ++j) acc[i][j] = fmaxf(acc[i][j], 0.f);

    if (type == 0 || type == 2) {
        const size_t regbase = (type == 2) ? (size_t)BATCH * CH * HW : 0;
#pragma unroll
        for (int i = 0; i < 8; ++i) {
            const int oo = o0 + ty * 8 + i;   // 0..511 within region
            float* dst = dout + regbase + ((size_t)b * CH + oo) * HW + n0 + tx * 8;
            *(float4*)dst       = make_float4(acc[i][0], acc[i][1], acc[i][2], acc[i][3]);
            *(float4*)(dst + 4) = make_float4(acc[i][4], acc[i][5], acc[i][6], acc[i][7]);
        }
    } else if (type == 1) {
        // spatial-sum of relu(g_x) for this n-tile, one atomic per (o, block)
#pragma unroll
        for (int i = 0; i < 8; ++i) {
            float s = 0.f;
#pragma unroll
            for (int j = 0; j < 8; ++j) s += acc[i][j];
            red[ty * 8 + i][tx] = s;
        }
        __syncthreads();
        if (tid < 128) {
            float s = 0.f;
#pragma unroll
            for (int t = 0; t < 16; ++t) s += red[tid][t];
            atomicAdd(&gmean[b * CH + o0 + tid], s);
        }
    } else {
        // only row o==1536 (local row 0) is valid -> mask_pre
        if (ty == 0) {
            float* dst = maskp + (size_t)b * HW + n0 + tx * 8;
            *(float4*)dst       = make_float4(acc[0][0], acc[0][1], acc[0][2], acc[0][3]);
            *(float4*)(dst + 4) = make_float4(acc[0][4], acc[0][5], acc[0][6], acc[0][7]);
        }
    }
}

// softmax over hw (4096) per batch, in place
__global__ __launch_bounds__(256) void softmax_hw_k(float* __restrict__ m)
{
    const int b = blockIdx.x;
    float* row = m + (size_t)b * HW;
    __shared__ float red[256];
    const int tid = threadIdx.x;
    float mx = -1e30f;
    for (int i = tid; i < HW; i += 256) mx = fmaxf(mx, row[i]);
    red[tid] = mx; __syncthreads();
    for (int s = 128; s > 0; s >>= 1) { if (tid < s) red[tid] = fmaxf(red[tid], red[tid + s]); __syncthreads(); }
    mx = red[0]; __syncthreads();
    float sum = 0.f;
    for (int i = tid; i < HW; i += 256) { float e = __expf(row[i] - mx); row[i] = e; sum += e; }
    red[tid] = sum; __syncthreads();
    for (int s = 128; s > 0; s >>= 1) { if (tid < s) red[tid] += red[tid + s]; __syncthreads(); }
    const float inv = 1.f / red[0];
    for (int i = tid; i < HW; i += 256) row[i] *= inv;
}

// gmean (spatial sums) -> /HW -> softmax over 512 channels -> avgx
__global__ __launch_bounds__(256) void softmax_ch_k(const float* __restrict__ gmean,
                                                    float* __restrict__ avgx)
{
    const int b = blockIdx.x;
    const float* src = gmean + b * CH;
    float* dst = avgx + b * CH;
    __shared__ float red[256];
    const int tid = threadIdx.x;
    const float v0 = src[tid]       * (1.f / HW);
    const float v1 = src[tid + 256] * (1.f / HW);
    red[tid] = fmaxf(v0, v1); __syncthreads();
    for (int s = 128; s > 0; s >>= 1) { if (tid < s) red[tid] = fmaxf(red[tid], red[tid + s]); __syncthreads(); }
    const float mx = red[0]; __syncthreads();
    const float e0 = __expf(v0 - mx), e1 = __expf(v1 - mx);
    red[tid] = e0 + e1; __syncthreads();
    for (int s = 128; s > 0; s >>= 1) { if (tid < s) red[tid] += red[tid + s]; __syncthreads(); }
    const float inv = 1.f / red[0];
    dst[tid] = e0 * inv; dst[tid + 256] = e1 * inv;
}

// context[b,c] = sum_n input_x[b,c,n] * mask[b,n]
__global__ __launch_bounds__(256) void ctx_k(const float* __restrict__ inputx,
                                             const float* __restrict__ mask,
                                             float* __restrict__ ctx)
{
    const int c = blockIdx.x, b = blockIdx.y;
    const float* row  = inputx + ((size_t)b * CH + c) * HW;
    const float* mrow = mask + (size_t)b * HW;
    __shared__ float red[256];
    const int tid = threadIdx.x;
    float s = 0.f;
    for (int i = tid; i < HW; i += 256) s = fmaf(row[i], mrow[i], s);
    red[tid] = s; __syncthreads();
    for (int t = 128; t > 0; t >>= 1) { if (tid < t) red[tid] += red[tid + t]; __syncthreads(); }
    if (tid == 0) ctx[b * CH + c] = red[0];
}

// layer_norm over 512 channels (no affine) -> sigmoid -> spatial_attn
__global__ __launch_bounds__(256) void ln_sig_k(const float* __restrict__ ctx,
                                                float* __restrict__ sattn)
{
    const int b = blockIdx.x;
    const float* src = ctx + b * CH;
    __shared__ float red[256];
    const int tid = threadIdx.x;
    const float v0 = src[tid], v1 = src[tid + 256];
    red[tid] = v0 + v1; __syncthreads();
    for (int s = 128; s > 0; s >>= 1) { if (tid < s) red[tid] += red[tid + s]; __syncthreads(); }
    const float mu = red[0] * (1.f / CH); __syncthreads();
    const float d0 = v0 - mu, d1 = v1 - mu;
    red[tid] = d0 * d0 + d1 * d1; __syncthreads();
    for (int s = 128; s > 0; s >>= 1) { if (tid < s) red[tid] += red[tid + s]; __syncthreads(); }
    const float rs = rsqrtf(red[0] * (1.f / CH) + LN_EPS);
    sattn[b * CH + tid]       = sigmoidf_(d0 * rs);
    sattn[b * CH + tid + 256] = sigmoidf_(d1 * rs);
}

// channel_attn[b,n] = sigmoid(sum_c avg_x[b,c] * theta_x[b,c,n])
__global__ __launch_bounds__(256) void cattn_k(const float* __restrict__ theta,
                                               const float* __restrict__ avgx,
                                               float* __restrict__ cattn)
{
    const int b = blockIdx.y;
    const int tid = threadIdx.x;
    const int n4 = (blockIdx.x * 256 + tid) * 4;   // gridDim.x = 4 covers 4096
    __shared__ float sa[CH];
    sa[tid]       = avgx[b * CH + tid];
    sa[tid + 256] = avgx[b * CH + tid + 256];
    __syncthreads();
    const float* tb = theta + (size_t)b * CH * HW + n4;
    float4 acc = make_float4(0.f, 0.f, 0.f, 0.f);
    for (int c = 0; c < CH; ++c) {
        const float4 t = *(const float4*)(tb + (size_t)c * HW);
        const float w = sa[c];
        acc.x = fmaf(w, t.x, acc.x); acc.y = fmaf(w, t.y, acc.y);
        acc.z = fmaf(w, t.z, acc.z); acc.w = fmaf(w, t.w, acc.w);
    }
    float4 o;
    o.x = sigmoidf_(acc.x); o.y = sigmoidf_(acc.y);
    o.z = sigmoidf_(acc.z); o.w = sigmoidf_(acc.w);
    *(float4*)(cattn + (size_t)b * HW + n4) = o;
}

// out = x * (1 + attn); attn = c<512 ? sa[c]*ca[n] : sa[c-512]+ca[n]
__global__ __launch_bounds__(256) void final_k(const float* __restrict__ x,
                                               const float* __restrict__ sattn,
                                               const float* __restrict__ cattn,
                                               float* __restrict__ out)
{
    const int c = blockIdx.x;   // 0..1023
    const int b = blockIdx.y;
    const float s = sattn[b * CH + (c & (CH - 1))];
    const bool seq = c < CH;
    const float4* xr = (const float4*)(x + ((size_t)b * CIN + c) * HW);
    const float4* cr = (const float4*)(cattn + (size_t)b * HW);
    float4* orow = (float4*)(out + ((size_t)b * CIN + c) * HW);
    for (int i = threadIdx.x; i < HW / 4; i += 256) {
        const float4 xv = xr[i], cv = cr[i];
        float4 f;
        if (seq) { f.x = s * cv.x; f.y = s * cv.y; f.z = s * cv.z; f.w = s * cv.w; }
        else     { f.x = s + cv.x; f.y = s + cv.y; f.z = s + cv.z; f.w = s + cv.w; }
        float4 o;
        o.x = fmaf(xv.x, f.x, xv.x);
        o.y = fmaf(xv.y, f.y, xv.y);
        o.z = fmaf(xv.z, f.z, xv.z);
        o.w = fmaf(xv.w, f.w, xv.w);
        orow[i] = o;
    }
}

extern "C" void kernel_launch(void* const* d_in, const int* in_sizes, int n_in,
                              void* d_out, int out_size, void* d_ws, size_t ws_size,
                              hipStream_t stream)
{
    const float* x    = (const float*)d_in[0];
    const float* w_qr = (const float*)d_in[1];
    const float* w_vr = (const float*)d_in[2];
    const float* w_ql = (const float*)d_in[3];
    const float* w_vl = (const float*)d_in[4];
    float* out = (float*)d_out;

    // small scratch in ws (~660 KB total)
    float* ws    = (float*)d_ws;
    float* maskp = ws;                       // 16*4096 (mask_pre, softmaxed in place)
    float* gmean = maskp + BATCH * HW;       // 16*512
    float* avgx  = gmean + BATCH * CH;       // 16*512
    float* ctx   = avgx  + BATCH * CH;       // 16*512
    float* sattn = ctx   + BATCH * CH;       // 16*512
    float* cattn = sattn + BATCH * CH;       // 16*4096

    // big intermediates live in d_out until the final pass overwrites it:
    float* inputx = out;                            // region A: (b,512,4096)
    float* theta  = out + (size_t)BATCH * CH * HW;  // region B: (b,512,4096)

    hipMemsetAsync(gmean, 0, BATCH * CH * sizeof(float), stream);

    gemm_conv<<<dim3(32, 13, BATCH), 256, 0, stream>>>(x, w_qr, w_vr, w_ql, w_vl,
                                                       out, maskp, gmean);
    softmax_hw_k<<<BATCH, 256, 0, stream>>>(maskp);
    softmax_ch_k<<<BATCH, 256, 0, stream>>>(gmean, avgx);
    ctx_k<<<dim3(CH, BATCH), 256, 0, stream>>>(inputx, maskp, ctx);
    ln_sig_k<<<BATCH, 256, 0, stream>>>(ctx, sattn);
    cattn_k<<<dim3(4, BATCH), 256, 0, stream>>>(theta, avgx, cattn);
    final_k<<<dim3(CIN, BATCH), 256, 0, stream>>>(x, sattn, cattn, out);
}

// Round 2
// 981.987 us; speedup vs baseline: 2.9580x; 2.9580x over previous
//
#include <hip/hip_runtime.h>
#include <cstdint>
#include <cstddef>

#define BATCH 16
#define CIN   1024
#define CH    512
#define HW    4096

static constexpr float LN_EPS = 1e-5f;

typedef __bf16 bf16x8 __attribute__((ext_vector_type(8)));
typedef float  f32x4  __attribute__((ext_vector_type(4)));

__device__ __forceinline__ float sigmoidf_(float v) { return 1.0f / (1.0f + __expf(-v)); }

// fp32 -> bf16 bits, round-to-nearest-even
__device__ __forceinline__ unsigned short f2bf(float f) {
    union { float f; uint32_t u; } c; c.f = f;
    uint32_t r = (c.u + 0x7fffu + ((c.u >> 16) & 1u)) >> 16;
    return (unsigned short)r;
}

#define GLOAD_LDS16(g, l)                                                  \
    __builtin_amdgcn_global_load_lds(                                      \
        (const __attribute__((address_space(1))) void*)(g),                \
        (__attribute__((address_space(3))) void*)(l), 16, 0, 0)

// ---------------------------------------------------------------------------
// x[b,c,n] fp32 -> xt[b,n,c] bf16 (transpose so k=c is contiguous for MFMA)
// ---------------------------------------------------------------------------
__global__ __launch_bounds__(256) void transpose_convert(
    const float* __restrict__ x, unsigned short* __restrict__ xt)
{
    const int b  = blockIdx.z;
    const int c0 = blockIdx.y * 64;
    const int n0 = blockIdx.x * 64;
    __shared__ float t[64][65];
    const int tid = threadIdx.x;
    const int tx = tid & 15, ty = tid >> 4;
    const float* xb = x + ((size_t)b * CIN + c0) * HW + n0;
#pragma unroll
    for (int rr = 0; rr < 4; ++rr) {
        const int row = ty + rr * 16;
        float4 v = *(const float4*)(xb + (size_t)row * HW + tx * 4);
        t[row][tx * 4 + 0] = v.x; t[row][tx * 4 + 1] = v.y;
        t[row][tx * 4 + 2] = v.z; t[row][tx * 4 + 3] = v.w;
    }
    __syncthreads();
    const int n  = tid >> 2;
    const int cp = (tid & 3) * 16;
    __align__(16) unsigned short tmp[16];
#pragma unroll
    for (int i = 0; i < 16; ++i) tmp[i] = f2bf(t[cp + i][n]);
    unsigned short* dst = xt + ((size_t)b * HW + n0 + n) * CIN + c0 + cp;
    ((uint4*)dst)[0] = ((const uint4*)tmp)[0];
    ((uint4*)dst)[1] = ((const uint4*)tmp)[1];
}

// ---------------------------------------------------------------------------
// stacked weight convert: wA (640 rows: w_ql[512] + w_qr[1] + zero pad),
//                         wB (1024 rows: w_vr[512] + w_vl[512])
// ---------------------------------------------------------------------------
__global__ __launch_bounds__(256) void wconvert(
    const float* __restrict__ wqr, const float* __restrict__ wvr,
    const float* __restrict__ wql, const float* __restrict__ wvl,
    unsigned short* __restrict__ wA, unsigned short* __restrict__ wB)
{
    const int idx = blockIdx.x * 256 + threadIdx.x;
    if (idx < 640 * 1024) {
        const int row = idx >> 10, col = idx & 1023;
        float v = 0.f;
        if (row < 512)       v = wql[row * 1024 + col];
        else if (row == 512) v = wqr[col];
        wA[idx] = f2bf(v);
    } else {
        const int j = idx - 640 * 1024;
        const int row = j >> 10, col = j & 1023;
        const float v = (row < 512) ? wvr[row * 1024 + col] : wvl[(row - 512) * 1024 + col];
        wB[j] = f2bf(v);
    }
}

// ---------------------------------------------------------------------------
// MFMA bf16 GEMM, 128x128 tile, BK=32, 16x16x32 mfma, 4 waves (2x2 of 64x64).
// LDS layout: chunk(quad, row) = 16B of [row][k=quad*8..+7]; addr=chunk*16B.
// phase 0: mt 0-3 -> gmean (sum_n relu), mt 4 row 0 -> mask_pre.
// phase 1: mt 0-3 -> ctx += relu*mask (sum_n); mt 4-7 -> cattnp += relu*avgx
//          (sum_m). Nothing big is materialized.
// ---------------------------------------------------------------------------
__global__ __launch_bounds__(256) void mfma_gemm(
    const unsigned short* __restrict__ xt,   // [b][n][c] bf16
    const unsigned short* __restrict__ wst,  // stacked weights bf16 [o][c]
    const int phase,
    const float* __restrict__ maskp,         // phase 1 in
    const float* __restrict__ avgx,          // phase 1 in
    float* __restrict__ gmean,               // phase 0 out
    float* __restrict__ maskpre,             // phase 0 out
    float* __restrict__ ctx,                 // phase 1 out
    float* __restrict__ cattnp)              // phase 1 out
{
    const int b  = blockIdx.z;
    const int mt = blockIdx.y;
    const int n0 = blockIdx.x * 128;
    const int o0 = mt * 128;

    const int tid  = threadIdx.x;
    const int w    = tid >> 6;
    const int lane = tid & 63;
    const int wm = (w >> 1) * 64;
    const int wn = (w & 1) * 64;

    __shared__ __align__(16) unsigned short As[4 * 128 * 8];
    __shared__ __align__(16) unsigned short Bs[4 * 128 * 8];

    f32x4 acc[4][4];
#pragma unroll
    for (int mi = 0; mi < 4; ++mi)
#pragma unroll
        for (int nj = 0; nj < 4; ++nj) acc[mi][nj] = (f32x4){0.f, 0.f, 0.f, 0.f};

    // staging: 512 chunks per matrix; wave w instr s covers chunks [(w*2+s)*64, +64)
    const int ch0 = (w * 2 + 0) * 64 + lane;
    const int ch1 = (w * 2 + 1) * 64 + lane;
    const int qA0 = ch0 >> 7, rA0 = ch0 & 127;
    const int qA1 = ch1 >> 7, rA1 = ch1 & 127;
    const unsigned short* gA0 = wst + (size_t)(o0 + rA0) * CIN + qA0 * 8;
    const unsigned short* gA1 = wst + (size_t)(o0 + rA1) * CIN + qA1 * 8;
    const unsigned short* gB0 = xt + ((size_t)b * HW + n0 + rA0) * CIN + qA0 * 8;
    const unsigned short* gB1 = xt + ((size_t)b * HW + n0 + rA1) * CIN + qA1 * 8;
    unsigned short* ldsA0 = As + (w * 2 + 0) * 64 * 8;
    unsigned short* ldsA1 = As + (w * 2 + 1) * 64 * 8;
    unsigned short* ldsB0 = Bs + (w * 2 + 0) * 64 * 8;
    unsigned short* ldsB1 = Bs + (w * 2 + 1) * 64 * 8;

    const int qr = (lane >> 4) * 128;
    const int lr = lane & 15;

    for (int c0 = 0; c0 < CIN; c0 += 32) {
        __syncthreads();                 // all waves done reading previous tile
        GLOAD_LDS16(gA0 + c0, ldsA0);
        GLOAD_LDS16(gA1 + c0, ldsA1);
        GLOAD_LDS16(gB0 + c0, ldsB0);
        GLOAD_LDS16(gB1 + c0, ldsB1);
        __syncthreads();                 // drains vmcnt -> LDS data visible
        bf16x8 af[4], bfr[4];
#pragma unroll
        for (int mi = 0; mi < 4; ++mi)
            af[mi] = *(const bf16x8*)(As + (size_t)(qr + wm + mi * 16 + lr) * 8);
#pragma unroll
        for (int nj = 0; nj < 4; ++nj)
            bfr[nj] = *(const bf16x8*)(Bs + (size_t)(qr + wn + nj * 16 + lr) * 8);
#pragma unroll
        for (int mi = 0; mi < 4; ++mi)
#pragma unroll
            for (int nj = 0; nj < 4; ++nj)
                acc[mi][nj] = __builtin_amdgcn_mfma_f32_16x16x32_bf16(
                    af[mi], bfr[nj], acc[mi][nj], 0, 0, 0);
    }

    // ---- epilogues (C/D layout: col = lane&15, row = (lane>>4)*4 + reg) ----
    const int quad = lane >> 4;
    if (phase == 0) {
        if (mt < 4) {
            // gmean[b][o] += sum_n relu
#pragma unroll
            for (int mi = 0; mi < 4; ++mi)
#pragma unroll
                for (int r = 0; r < 4; ++r) {
                    float v = 0.f;
#pragma unroll
                    for (int nj = 0; nj < 4; ++nj) v += fmaxf(acc[mi][nj][r], 0.f);
                    v += __shfl_xor(v, 1); v += __shfl_xor(v, 2);
                    v += __shfl_xor(v, 4); v += __shfl_xor(v, 8);
                    if (lr == 0)
                        atomicAdd(&gmean[b * CH + o0 + wm + mi * 16 + quad * 4 + r], v);
                }
        } else {
            // global row 512 (w_qr) = local row 0: wm==0, mi==0, quad==0, reg 0
            if (wm == 0 && quad == 0) {
#pragma unroll
                for (int nj = 0; nj < 4; ++nj)
                    maskpre[(size_t)b * HW + n0 + wn + nj * 16 + lr] =
                        fmaxf(acc[0][nj][0], 0.f);
            }
        }
    } else {
        if (mt < 4) {
            // ctx[b][o] += sum_n relu * mask[n]
            float mk[4];
#pragma unroll
            for (int nj = 0; nj < 4; ++nj)
                mk[nj] = maskp[(size_t)b * HW + n0 + wn + nj * 16 + lr];
#pragma unroll
            for (int mi = 0; mi < 4; ++mi)
#pragma unroll
                for (int r = 0; r < 4; ++r) {
                    float v = 0.f;
#pragma unroll
                    for (int nj = 0; nj < 4; ++nj)
                        v += fmaxf(acc[mi][nj][r], 0.f) * mk[nj];
                    v += __shfl_xor(v, 1); v += __shfl_xor(v, 2);
                    v += __shfl_xor(v, 4); v += __shfl_xor(v, 8);
                    if (lr == 0)
                        atomicAdd(&ctx[b * CH + o0 + wm + mi * 16 + quad * 4 + r], v);
                }
        } else {
            // cattnp[b][n] += sum_m relu * avgx[m]   (m-rows 512.. -> avgx idx o0-512)
            float colsum[4] = {0.f, 0.f, 0.f, 0.f};
#pragma unroll
            for (int mi = 0; mi < 4; ++mi) {
                float aw[4];
#pragma unroll
                for (int r = 0; r < 4; ++r)
                    aw[r] = avgx[b * CH + (o0 - 512) + wm + mi * 16 + quad * 4 + r];
#pragma unroll
                for (int nj = 0; nj < 4; ++nj)
#pragma unroll
                    for (int r = 0; r < 4; ++r)
                        colsum[nj] += fmaxf(acc[mi][nj][r], 0.f) * aw[r];
            }
#pragma unroll
            for (int nj = 0; nj < 4; ++nj) {
                float v = colsum[nj];
                v += __shfl_xor(v, 16);
                v += __shfl_xor(v, 32);
                if (lane < 16)
                    atomicAdd(&cattnp[(size_t)b * HW + n0 + wn + nj * 16 + lane], v);
            }
        }
    }
}

// softmax over hw (4096) per batch, in place
__global__ __launch_bounds__(256) void softmax_hw_k(float* __restrict__ m)
{
    const int b = blockIdx.x;
    float* row = m + (size_t)b * HW;
    __shared__ float red[256];
    const int tid = threadIdx.x;
    float mx = -1e30f;
    for (int i = tid; i < HW; i += 256) mx = fmaxf(mx, row[i]);
    red[tid] = mx; __syncthreads();
    for (int s = 128; s > 0; s >>= 1) { if (tid < s) red[tid] = fmaxf(red[tid], red[tid + s]); __syncthreads(); }
    mx = red[0]; __syncthreads();
    float sum = 0.f;
    for (int i = tid; i < HW; i += 256) { float e = __expf(row[i] - mx); row[i] = e; sum += e; }
    red[tid] = sum; __syncthreads();
    for (int s = 128; s > 0; s >>= 1) { if (tid < s) red[tid] += red[tid + s]; __syncthreads(); }
    const float inv = 1.f / red[0];
    for (int i = tid; i < HW; i += 256) row[i] *= inv;
}

// gmean (spatial sums) -> /HW -> softmax over 512 channels -> avgx
__global__ __launch_bounds__(256) void softmax_ch_k(const float* __restrict__ gmean,
                                                    float* __restrict__ avgx)
{
    const int b = blockIdx.x;
    const float* src = gmean + b * CH;
    float* dst = avgx + b * CH;
    __shared__ float red[256];
    const int tid = threadIdx.x;
    const float v0 = src[tid]       * (1.f / HW);
    const float v1 = src[tid + 256] * (1.f / HW);
    red[tid] = fmaxf(v0, v1); __syncthreads();
    for (int s = 128; s > 0; s >>= 1) { if (tid < s) red[tid] = fmaxf(red[tid], red[tid + s]); __syncthreads(); }
    const float mx = red[0]; __syncthreads();
    const float e0 = __expf(v0 - mx), e1 = __expf(v1 - mx);
    red[tid] = e0 + e1; __syncthreads();
    for (int s = 128; s > 0; s >>= 1) { if (tid < s) red[tid] += red[tid + s]; __syncthreads(); }
    const float inv = 1.f / red[0];
    dst[tid] = e0 * inv; dst[tid + 256] = e1 * inv;
}

// layer_norm over 512 channels (no affine) -> sigmoid -> spatial_attn
__global__ __launch_bounds__(256) void ln_sig_k(const float* __restrict__ ctx,
                                                float* __restrict__ sattn)
{
    const int b = blockIdx.x;
    const float* src = ctx + b * CH;
    __shared__ float red[256];
    const int tid = threadIdx.x;
    const float v0 = src[tid], v1 = src[tid + 256];
    red[tid] = v0 + v1; __syncthreads();
    for (int s = 128; s > 0; s >>= 1) { if (tid < s) red[tid] += red[tid + s]; __syncthreads(); }
    const float mu = red[0] * (1.f / CH); __syncthreads();
    const float d0 = v0 - mu, d1 = v1 - mu;
    red[tid] = d0 * d0 + d1 * d1; __syncthreads();
    for (int s = 128; s > 0; s >>= 1) { if (tid < s) red[tid] += red[tid + s]; __syncthreads(); }
    const float rs = rsqrtf(red[0] * (1.f / CH) + LN_EPS);
    sattn[b * CH + tid]       = sigmoidf_(d0 * rs);
    sattn[b * CH + tid + 256] = sigmoidf_(d1 * rs);
}

// out = x * (1 + attn); attn = c<512 ? sa[c]*sig(cp[n]) : sa[c-512]+sig(cp[n])
__global__ __launch_bounds__(256) void final_k(const float* __restrict__ x,
                                               const float* __restrict__ sattn,
                                               const float* __restrict__ cattnp,
                                               float* __restrict__ out)
{
    const int c = blockIdx.x;   // 0..1023
    const int b = blockIdx.y;
    const float s = sattn[b * CH + (c & (CH - 1))];
    const bool seq = c < CH;
    const float4* xr = (const float4*)(x + ((size_t)b * CIN + c) * HW);
    const float4* cr = (const float4*)(cattnp + (size_t)b * HW);
    float4* orow = (float4*)(out + ((size_t)b * CIN + c) * HW);
    for (int i = threadIdx.x; i < HW / 4; i += 256) {
        const float4 xv = xr[i], cp = cr[i];
        float4 cv;
        cv.x = sigmoidf_(cp.x); cv.y = sigmoidf_(cp.y);
        cv.z = sigmoidf_(cp.z); cv.w = sigmoidf_(cp.w);
        float4 f;
        if (seq) { f.x = s * cv.x; f.y = s * cv.y; f.z = s * cv.z; f.w = s * cv.w; }
        else     { f.x = s + cv.x; f.y = s + cv.y; f.z = s + cv.z; f.w = s + cv.w; }
        float4 o;
        o.x = fmaf(xv.x, f.x, xv.x);
        o.y = fmaf(xv.y, f.y, xv.y);
        o.z = fmaf(xv.z, f.z, xv.z);
        o.w = fmaf(xv.w, f.w, xv.w);
        orow[i] = o;
    }
}

extern "C" void kernel_launch(void* const* d_in, const int* in_sizes, int n_in,
                              void* d_out, int out_size, void* d_ws, size_t ws_size,
                              hipStream_t stream)
{
    const float* x    = (const float*)d_in[0];
    const float* w_qr = (const float*)d_in[1];
    const float* w_vr = (const float*)d_in[2];
    const float* w_ql = (const float*)d_in[3];
    const float* w_vl = (const float*)d_in[4];
    float* out = (float*)d_out;

    // big scratch carved out of d_out (268 MB); all consumed before final_k writes
    unsigned short* xt = (unsigned short*)d_out;             // [b][n][c] bf16, 134 MB
    unsigned short* wA = xt + (size_t)BATCH * HW * CIN;      // 640*1024 bf16
    unsigned short* wB = wA + 640 * CIN;                     // 1024*1024 bf16

    // small scratch in ws (~660 KB)
    float* ws     = (float*)d_ws;
    float* maskp  = ws;                      // 16*4096 (pre-softmax, then in-place)
    float* avgx   = maskp + BATCH * HW;      // 16*512
    float* sattn  = avgx  + BATCH * CH;      // 16*512
    float* gmean  = sattn + BATCH * CH;      // 16*512  -- zero-init region start
    float* ctx    = gmean + BATCH * CH;      // 16*512
    float* cattnp = ctx   + BATCH * CH;      // 16*4096

    hipMemsetAsync(gmean, 0, (size_t)(BATCH * CH * 2 + BATCH * HW) * sizeof(float), stream);

    wconvert<<<6656, 256, 0, stream>>>(w_qr, w_vr, w_ql, w_vl, wA, wB);
    transpose_convert<<<dim3(HW / 64, CIN / 64, BATCH), 256, 0, stream>>>(x, xt);

    mfma_gemm<<<dim3(HW / 128, 5, BATCH), 256, 0, stream>>>(
        xt, wA, 0, nullptr, nullptr, gmean, maskp, nullptr, nullptr);
    softmax_hw_k<<<BATCH, 256, 0, stream>>>(maskp);
    softmax_ch_k<<<BATCH, 256, 0, stream>>>(gmean, avgx);
    mfma_gemm<<<dim3(HW / 128, 8, BATCH), 256, 0, stream>>>(
        xt, wB, 1, maskp, avgx, nullptr, nullptr, ctx, cattnp);
    ln_sig_k<<<BATCH, 256, 0, stream>>>(ctx, sattn);
    final_k<<<dim3(CIN, BATCH), 256, 0, stream>>>(x, sattn, cattnp, out);
}